// Round 10
// baseline (356.241 us; speedup 1.0000x reference)
//
#include <hip/hip_runtime.h>

// MultiHeadAttention: B=4, S=2048, D=1024, H=16, dk=dv=64.
// Inputs fp32, output fp32; compute bf16 MFMA.
// R10: attention: 64 q per wave (4 subtiles -> kf/vf reads amortized 4x),
// ds_permute one-to-one P^T delivery (16 vs 32 DS ops), stride-70 padded LDS
// (reads ~2-way, writes 2-way=free), register staging (no DMA), 128-thr WGs.

typedef __attribute__((ext_vector_type(8))) short bf16x8;   // 8 bf16 = 4 VGPRs
typedef __attribute__((ext_vector_type(4))) float f32x4;
typedef __attribute__((ext_vector_type(4))) unsigned short ushortx4;

__device__ __forceinline__ unsigned short f2bf(float x) {   // RNE
    unsigned int u = __float_as_uint(x);
    u += 0x7FFFu + ((u >> 16) & 1u);
    return (unsigned short)(u >> 16);
}
// pack two floats as truncated bf16 pair: [hi.bf16 : lo.bf16]
__device__ __forceinline__ unsigned int pack_bf2(float hi, float lo) {
    return (__float_as_uint(hi) & 0xFFFF0000u) | (__float_as_uint(lo) >> 16);
}

// async 16B global -> LDS (lds dest wave-uniform; HW adds lane*16)
__device__ __forceinline__ void gload_lds16(const unsigned short* g, unsigned short* lds) {
    __builtin_amdgcn_global_load_lds(
        (const __attribute__((address_space(1))) unsigned int*)g,
        (__attribute__((address_space(3))) unsigned int*)lds,
        16, 0, 0);
}

// ---------------------------------------------------------------------------
// One merged pack kernel. Sections by blockIdx.x:
//  [0,4096):      XB  = bf16(x)
//  [4096,5632):   WQKVT[n][d] (Wq pre-scaled by 0.125*log2e)
//  [5632,6144):   WOT[n][k] = Wo[k][n]
__global__ __launch_bounds__(256) void pack_all(
    const float* __restrict__ x,
    const float* __restrict__ Wq,
    const float* __restrict__ Wk,
    const float* __restrict__ Wv,
    const float* __restrict__ Wo,
    unsigned short* __restrict__ XB,
    unsigned short* __restrict__ WQKVT,
    unsigned short* __restrict__ WOT)
{
    const int bid = blockIdx.x;
    bf16x8 v;
    if (bid < 4096) {
        size_t base = ((size_t)bid * 256 + threadIdx.x) * 8;
        float4 f0 = *(const float4*)&x[base];
        float4 f1 = *(const float4*)&x[base + 4];
        v[0] = f2bf(f0.x); v[1] = f2bf(f0.y); v[2] = f2bf(f0.z); v[3] = f2bf(f0.w);
        v[4] = f2bf(f1.x); v[5] = f2bf(f1.y); v[6] = f2bf(f1.z); v[7] = f2bf(f1.w);
        *(bf16x8*)&XB[base] = v;
    } else if (bid < 5632) {
        int i = (bid - 4096) * 256 + threadIdx.x;
        int d0 = (i * 8) & 1023;
        int n  = (i * 8) >> 10;
        int part = n >> 10;
        int hkk  = n & 1023;
        int h = hkk >> 6, kk = hkk & 63;
        const float* W = (part == 0) ? Wq : ((part == 1) ? Wk : Wv);
        float scale = (part == 0) ? 0.125f * 1.44269504088896f : 1.0f;
        #pragma unroll
        for (int e = 0; e < 8; ++e)
            v[e] = f2bf(W[(h << 16) + ((d0 + e) << 6) + kk] * scale);
        *(bf16x8*)&WQKVT[(size_t)n * 1024 + d0] = v;
    } else {
        int i = (bid - 5632) * 256 + threadIdx.x;
        int k0 = (i * 8) & 1023;
        int n  = (i * 8) >> 10;
        #pragma unroll
        for (int e = 0; e < 8; ++e)
            v[e] = f2bf(Wo[(size_t)(k0 + e) * 1024 + n]);
        *(bf16x8*)&WOT[(size_t)n * 1024 + k0] = v;
    }
}

// ---------------------------------------------------------------------------
// C = A[M][K] @ Bt[N][K]^T, A/Bt bf16 row-major, global_load_lds staging.
// CMODE 0: C fp32 ldc.  CMODE 1: QKV split (QK bf16 / VT transposed).
// BN=128: 4 waves 2x2, 4x4 frags.  BN=64: 4 waves 4x1, 2x4 frags.
template<int CMODE, int BN>
__global__ __launch_bounds__(256) void gemm_bt(
    const unsigned short* __restrict__ A,
    const unsigned short* __restrict__ Bt,
    void* __restrict__ Cv,
    unsigned short* __restrict__ VT,
    int M, int N, int K, int ldc)
{
    __shared__ __align__(16) unsigned short As[128 * 32];
    __shared__ __align__(16) unsigned short Bs[BN * 32];
    const int m0 = blockIdx.y * 128;
    const int n0 = blockIdx.x * BN;
    const int tid  = threadIdx.x;
    const int w    = tid >> 6, lane = tid & 63;
    const int q4   = lane >> 4, lr  = lane & 15;
    constexpr int MI = (BN == 128) ? 4 : 2;
    const int rowBase = (BN == 128) ? (w >> 1) * 64 : w * 32;
    const int colBase = (BN == 128) ? (w & 1) * 64 : 0;

    const int ch   = tid & 3;
    const int row0 = tid >> 2;
    unsigned short* asb0 = &As[w * 512];
    unsigned short* asb1 = &As[2048 + w * 512];
    unsigned short* bsb0 = &Bs[w * 512];
    unsigned short* bsb1 = (BN == 128) ? &Bs[2048 + w * 512] : nullptr;

    f32x4 acc[MI][4] = {};

    for (int k0 = 0; k0 < K; k0 += 32) {
        __syncthreads();
        gload_lds16(&A [(size_t)(m0 + row0)      * K + k0 + ch * 8], asb0);
        gload_lds16(&A [(size_t)(m0 + row0 + 64) * K + k0 + ch * 8], asb1);
        gload_lds16(&Bt[(size_t)(n0 + row0)      * K + k0 + ch * 8], bsb0);
        if (BN == 128)
            gload_lds16(&Bt[(size_t)(n0 + row0 + 64) * K + k0 + ch * 8], bsb1);
        __syncthreads();

        bf16x8 af[MI], bfv[4];
        #pragma unroll
        for (int i = 0; i < MI; ++i)
            af[i] = *(const bf16x8*)&As[(rowBase + i * 16 + lr) * 32 + q4 * 8];
        #pragma unroll
        for (int j = 0; j < 4; ++j)
            bfv[j] = *(const bf16x8*)&Bs[(colBase + j * 16 + lr) * 32 + q4 * 8];
        #pragma unroll
        for (int i = 0; i < MI; ++i)
            #pragma unroll
            for (int j = 0; j < 4; ++j)
                acc[i][j] = __builtin_amdgcn_mfma_f32_16x16x32_bf16(af[i], bfv[j], acc[i][j], 0, 0, 0);
    }

    #pragma unroll
    for (int i = 0; i < MI; ++i) {
        const int row = m0 + rowBase + i * 16 + q4 * 4;
        #pragma unroll
        for (int j = 0; j < 4; ++j) {
            const int col = n0 + colBase + j * 16 + lr;
            if (CMODE == 0) {
                float* C = (float*)Cv;
                #pragma unroll
                for (int p = 0; p < 4; ++p)
                    C[(size_t)(row + p) * ldc + col] = acc[i][j][p];
            } else {
                if (col < 2048) {
                    unsigned short* C = (unsigned short*)Cv;
                    #pragma unroll
                    for (int p = 0; p < 4; ++p)
                        C[(size_t)(row + p) * 2048 + col] = f2bf(acc[i][j][p]);
                } else {
                    const int c2 = col - 2048;
                    const int hh = c2 >> 6, dd = c2 & 63;
                    const int bb = row >> 11, ss = row & 2047;
                    ushortx4 v;
                    #pragma unroll
                    for (int p = 0; p < 4; ++p) v[p] = f2bf(acc[i][j][p]);
                    *(ushortx4*)&VT[((size_t)(bb * 16 + hh) * 64 + dd) * 2048 + ss] = v;
                }
            }
        }
    }
}

// ---------------------------------------------------------------------------
// Flash attention, transposed-P scheme, 64 q per wave.
// QK[8192][2048] bf16 (Q|K), VT[(b*16+h)*64+d][2048] bf16.
// WG = 128 threads (2 waves); wave w owns queries [w*64, w*64+64) of the
// WG's 128-q block as 4 subtiles u.  64-key tiles, stride-70 padded LDS,
// register staging, S^T = K·Q^T, P^T via 4 one-to-one ds_permutes per
// (kc,u), O^T = V^T·P^T.
__global__ __launch_bounds__(128, 2) void attn_flash(
    const unsigned short* __restrict__ QK,
    const unsigned short* __restrict__ VT,
    unsigned short* __restrict__ HC)        // [8192][1024] bf16
{
    const int bh  = blockIdx.x;   // b*16+h (fastest -> L2-shared K/V)
    const int qb  = blockIdx.y;   // 0..15
    const int b   = bh >> 4, h = bh & 15;
    const int tid = threadIdx.x;
    const int w   = tid >> 6, lane = tid & 63;
    const int q4  = lane >> 4, lr  = lane & 15;

    constexpr int LDS_S = 70;   // stride: reads ~2-way, writes 2-way (free)
    __shared__ __align__(16) unsigned short Ks [64 * LDS_S];   // [key][dk]
    __shared__ __align__(16) unsigned short Vts[64 * LDS_S];   // [d][key]

    // staging: thread t -> row t>>1 (0..63), 32-col half (t&1)*32
    const int sRow = tid >> 1;
    const int sCol = (tid & 1) * 32;
    const unsigned short* Kg = QK + (size_t)(b * 2048) * 2048 + 1024 + h * 64
                                  + (size_t)sRow * 2048 + sCol;
    const unsigned short* Vg = VT + (size_t)bh * 64 * 2048
                                  + (size_t)sRow * 2048 + sCol;

    bf16x8 kr[4], vr[4];
    auto issue_loads = [&](int kb) {
        const unsigned short* kg = Kg + (size_t)kb * 2048;
        const unsigned short* vg = Vg + kb;
        #pragma unroll
        for (int i = 0; i < 4; ++i) {
            kr[i] = *(const bf16x8*)(kg + i * 8);
            vr[i] = *(const bf16x8*)(vg + i * 8);
        }
    };
    auto write_lds = [&]() {
        #pragma unroll
        for (int i = 0; i < 4; ++i) {
            *(bf16x8*)&Ks [sRow * LDS_S + sCol + i * 8] = kr[i];
            *(bf16x8*)&Vts[sRow * LDS_S + sCol + i * 8] = vr[i];
        }
    };

    issue_loads(0);

    const int qrow0 = b * 2048 + qb * 128 + w * 64;
    bf16x8 qf[4][2];   // B-frag of Q^T: Q[q=u*16+lr][dk=c*32+q4*8+j], pre-scaled
    #pragma unroll
    for (int u = 0; u < 4; ++u)
        #pragma unroll
        for (int c = 0; c < 2; ++c)
            qf[u][c] = *(const bf16x8*)&QK[(size_t)(qrow0 + u * 16 + lr) * 2048
                                           + h * 64 + c * 32 + q4 * 8];

    // ds_permute dest addrs (dest_lane*4), constant per lane:
    //  P1: dest q4 = (q4&1)*2 + (q4>>1)   (payload pk[m1 = own q4&1])
    //  P3: dest q4 = (1-(q4&1))*2 + (q4>>1) (payload pk[1 - own q4&1])
    const int dstP1 = ((((q4 & 1) * 2 + (q4 >> 1)) * 16) + lr) * 4;
    const int dstP3 = ((((1 - (q4 & 1)) * 2 + (q4 >> 1)) * 16) + lr) * 4;
    const bool qlo = (q4 & 1) != 0;
    const bool hiSel = (q4 >= 2);

    f32x4 o[4][4] = {};      // O^T[d=jd*16+q4*4+p][q=u*16+lr]
    float lpart[4] = {};     // per-lane denominator partials (q = lr per u)

    for (int t = 0; t < 32; ++t) {
        __syncthreads();                       // waves done reading tile t-1
        write_lds();
        if (t + 1 < 32) issue_loads((t + 1) * 64);   // in flight during compute
        __syncthreads();                       // LDS tiles ready

        #pragma unroll
        for (int kc = 0; kc < 2; ++kc) {
            // --- S^T for key rows [kc*32, kc*32+32): mt = 2kc+m1
            unsigned int pk[4][2][2];          // [u][m1][i] packed P^T words
            #pragma unroll
            for (int m1 = 0; m1 < 2; ++m1) {
                const int mt = kc * 2 + m1;
                f32x4 st[4] = {};
                #pragma unroll
                for (int c = 0; c < 2; ++c) {
                    bf16x8 kf = *(const bf16x8*)&Ks[(mt * 16 + lr) * LDS_S + c * 32 + q4 * 8];
                    #pragma unroll
                    for (int u = 0; u < 4; ++u)
                        st[u] = __builtin_amdgcn_mfma_f32_16x16x32_bf16(kf, qf[u][c], st[u], 0, 0, 0);
                }
                #pragma unroll
                for (int u = 0; u < 4; ++u) {
                    float e0 = exp2f(st[u][0]);
                    float e1 = exp2f(st[u][1]);
                    float e2 = exp2f(st[u][2]);
                    float e3 = exp2f(st[u][3]);
                    lpart[u] += (e0 + e1) + (e2 + e3);
                    pk[u][m1][0] = pack_bf2(e1, e0);
                    pk[u][m1][1] = pack_bf2(e3, e2);
                }
            }

            // --- exchange P^T -> PV B-frags: 4 one-to-one ds_permutes per u
            bf16x8 pb[4];
            #pragma unroll
            for (int u = 0; u < 4; ++u) {
                unsigned int pay1 = qlo ? pk[u][1][0] : pk[u][0][0];
                unsigned int pay2 = qlo ? pk[u][1][1] : pk[u][0][1];
                unsigned int pay3 = qlo ? pk[u][0][0] : pk[u][1][0];
                unsigned int pay4 = qlo ? pk[u][0][1] : pk[u][1][1];
                int r1 = __builtin_amdgcn_ds_permute(dstP1, (int)pay1);
                int r2 = __builtin_amdgcn_ds_permute(dstP1, (int)pay2);
                int r3 = __builtin_amdgcn_ds_permute(dstP3, (int)pay3);
                int r4 = __builtin_amdgcn_ds_permute(dstP3, (int)pay4);
                int4 wv;
                wv.x = hiSel ? r3 : r1;
                wv.y = hiSel ? r4 : r2;
                wv.z = hiSel ? r1 : r3;
                wv.w = hiSel ? r2 : r4;
                pb[u] = *(bf16x8*)&wv;
            }

            // --- PV: O^T += V^T · P^T  (each vf feeds all 4 subtiles)
            #pragma unroll
            for (int jd = 0; jd < 4; ++jd) {
                bf16x8 vf = *(const bf16x8*)&Vts[(jd * 16 + lr) * LDS_S + kc * 32 + q4 * 8];
                #pragma unroll
                for (int u = 0; u < 4; ++u)
                    o[u][jd] = __builtin_amdgcn_mfma_f32_16x16x32_bf16(vf, pb[u], o[u][jd], 0, 0, 0);
            }
        }
    }

    #pragma unroll
    for (int u = 0; u < 4; ++u) {
        float l = lpart[u];
        l += __shfl_xor(l, 16);
        l += __shfl_xor(l, 32);
        const float inv = 1.0f / l;
        const size_t rowO = (size_t)(qrow0 + u * 16 + lr);
        #pragma unroll
        for (int jd = 0; jd < 4; ++jd) {
            ushortx4 v;
            #pragma unroll
            for (int p = 0; p < 4; ++p)
                v[p] = f2bf(o[u][jd][p] * inv);
            *(ushortx4*)&HC[rowO * 1024 + h * 64 + jd * 16 + q4 * 4] = v;
        }
    }
}

// ---------------------------------------------------------------------------
extern "C" void kernel_launch(void* const* d_in, const int* in_sizes, int n_in,
                              void* d_out, int out_size, void* d_ws, size_t ws_size,
                              hipStream_t stream)
{
    const float* x  = (const float*)d_in[0];
    const float* Wq = (const float*)d_in[1];
    const float* Wk = (const float*)d_in[2];
    const float* Wv = (const float*)d_in[3];
    const float* Wo = (const float*)d_in[4];
    float* out = (float*)d_out;

    char* ws = (char*)d_ws;
    unsigned short* XB    = (unsigned short*)(ws);              // 16777216 (aliases HC)
    unsigned short* HC    = (unsigned short*)(ws);
    unsigned short* WQKVT = (unsigned short*)(ws + 16777216);   // 6291456
    unsigned short* WOT   = (unsigned short*)(ws + 23068672);   // 2097152
    unsigned short* QK    = (unsigned short*)(ws + 25165824);   // 33554432
    unsigned short* VT    = (unsigned short*)(ws + 58720256);   // 16777216
    // total ws: 75497472 B (~72 MiB)

    pack_all<<<6144, 256, 0, stream>>>(x, Wq, Wk, Wv, Wo, XB, WQKVT, WOT);
    gemm_bt<1, 128><<<dim3(24, 64), 256, 0, stream>>>(XB, WQKVT, QK, VT, 8192, 3072, 1024, 0);
    attn_flash<<<dim3(64, 16), 128, 0, stream>>>(QK, VT, HC);
    gemm_bt<0, 64><<<dim3(16, 64), 256, 0, stream>>>(HC, WOT, out, nullptr, 8192, 1024, 1024, 1024);
}